// Round 7
// baseline (347.876 us; speedup 1.0000x reference)
//
#include <hip/hip_runtime.h>
#include <math.h>

#define KNN    10
#define NPTS   8192
#define HID    64
#define NF     76
#define CHUNKS 16
#define CLEN   (NPTS / CHUNKS)   // 512
#define CAP    64                // pass-2 collection capacity per query
#define F32_INF __uint_as_float(0x7F800000u)

// ---------------------------------------------------------------------------
// Prep: pts4[i] = (x, y, z, x^2+y^2+z^2)  (w chain identical to all rounds).
// ---------------------------------------------------------------------------
__global__ __launch_bounds__(256) void prep_kernel(const float* __restrict__ cloud,
                                                   float4* __restrict__ pts4) {
    const int i = blockIdx.x * 256 + threadIdx.x;      // 0..32767
    const float x = cloud[i * 3 + 0];
    const float y = cloud[i * 3 + 1];
    const float z = cloud[i * 3 + 2];
    pts4[i] = make_float4(x, y, z, fmaf(z, z, fmaf(y, y, x * x)));
}

// ---------------------------------------------------------------------------
// KNN via chunk-minima order statistics (no per-candidate top-10 anywhere):
// Pass 1: per (query, chunk) running MIN of v = pw - 2*dot (5 VALU/cand).
//   v-order == d2-order (d2 = qs + v up to rounding). Self lands in its own
//   chunk as v_self = -qs (global min of that chunk).
// tau: 11th smallest of the 16 chunk minima. Rank argument: the minima are a
//   16-subset containing at most one self entry; 11th of 16 >= 10th of the
//   >=15 real values >= true 10th-NN v. Convert to d2 domain with +1e-3
//   margin (covers f32 association differences, ~2e-5 worst case).
// Pass 2: recompute d2 with the EXACT R1-R5 expression (bitwise-identical
//   keys => final selection identical to all passing rounds); collect
//   (monotone(d2)<<13|j) for d2<=tau, expected ~21/query, CAP 64.
// Phase 3: wave 0, lane=query: bubble top-10 of collected keys (stable
//   (d2 asc, idx asc) == jax top_k). Uniform-branch exact serial fallback if
//   any count exceeded CAP (never expected; correctness net).
// Block = 1024 thr = 64 queries x 16 chunks; candidate loads wave-uniform.
// ---------------------------------------------------------------------------
__global__ __launch_bounds__(1024) void knn_kernel(const float4* __restrict__ pts4,
                                                   unsigned short* __restrict__ knn_idx) {
    __shared__ float pk[CHUNKS][64];                 // chunk v-minima, 4 KB
    __shared__ unsigned long long coll[CAP][65];     // [slot][query+pad], 33 KB
    __shared__ float tau[64];
    __shared__ int   cnt[64];

    const int t  = threadIdx.x;
    const int c  = t >> 6;                    // chunk 0..15 (wave id)
    const int ql = t & 63;                    // query slot
    const int bx = blockIdx.x;                // 0..511
    const int b  = bx >> 7;                   // batch
    const int n0 = (bx & 127) * 64;
    const int n  = n0 + ql;                   // batch-local query index

    const float4* pb = pts4 + b * NPTS;
    const float4 q = pb[n];
    const float qx = q.x, qy = q.y, qz = q.z, qs = q.w;

    const int cb0 = __builtin_amdgcn_readfirstlane(c * CLEN);

    // ---------------- pass 1: chunk minimum of v = pw - 2*dot ----------------
    float vmin = F32_INF;
#pragma unroll 8
    for (int i = 0; i < CLEN; ++i) {
        const float4 p = pb[cb0 + i];         // uniform -> s_load
        const float dot = fmaf(p.z, qz, fmaf(p.y, qy, p.x * qx));
        const float v = fmaf(-2.0f, dot, p.w);
        vmin = fminf(vmin, v);
    }
    pk[c][ql] = vmin;
    if (t < 64) cnt[t] = 0;
    __syncthreads();

    // wave 0: 11th smallest of the 16 chunk minima -> tau (d2 domain + margin)
    if (t < 64) {
        float md[KNN + 1];
#pragma unroll
        for (int s = 0; s <= KNN; ++s) md[s] = F32_INF;
#pragma unroll
        for (int cc = 0; cc < CHUNKS; ++cc) {
            float d = pk[cc][t];
#pragma unroll
            for (int u = 0; u <= KNN; ++u) {
                const float lo = fminf(md[u], d);
                d = fmaxf(md[u], d);
                md[u] = lo;
            }
        }
        tau[t] = qs + md[KNN] + 1e-3f;
    }
    __syncthreads();

    // ---------------- pass 2: exact collect (R1-R5-identical d2) ------------
    const float tq = tau[ql];
#pragma unroll 4
    for (int i = 0; i < CLEN; ++i) {
        const float4 p = pb[cb0 + i];
        const float dot = fmaf(p.z, qz, fmaf(p.y, qy, p.x * qx));
        const float d2 = fmaf(-2.0f, dot, qs + p.w);
        if (d2 <= tq) {                        // ~21/query expected
            if (cb0 + i != n) {
                const unsigned int fb = __float_as_uint(d2);
                const unsigned int m =
                    fb ^ ((unsigned int)((int)fb >> 31) | 0x80000000u);  // monotone
                const unsigned long long key =
                    ((unsigned long long)m << 13) | (unsigned long long)(cb0 + i);
                const int slot = atomicAdd(&cnt[ql], 1);
                if (slot < CAP) coll[slot][ql] = key;
            }
        }
    }
    __syncthreads();

    // ---------------- phase 3: exact stable top-10 ----------------
    if (t < 64) {
        const int m = cnt[t];
        int mc = m;
#pragma unroll
        for (int off = 1; off < 64; off <<= 1)
            mc = max(mc, __shfl_xor(mc, off, 64));
        mc = __builtin_amdgcn_readfirstlane(mc);

        unsigned long long md[KNN];
#pragma unroll
        for (int s = 0; s < KNN; ++s) md[s] = ~0ULL;

        if (mc <= CAP) {                       // normal path (uniform branch)
            for (int cc = 0; cc < mc; ++cc) {
                unsigned long long key = (cc < m) ? coll[cc][t] : ~0ULL;
#pragma unroll
                for (int u = 0; u < KNN; ++u) {
                    const bool lt = key < md[u];
                    const unsigned long long lo = lt ? key : md[u];
                    key = lt ? md[u] : key;
                    md[u] = lo;
                }
            }
        } else {
            // exact serial fallback (never expected): full rescan, branchless
            for (int j = 0; j < NPTS; ++j) {
                const float4 p = pb[j];        // uniform -> s_load
                const float dot = fmaf(p.z, qz, fmaf(p.y, qy, p.x * qx));
                const float d2 = fmaf(-2.0f, dot, qs + p.w);
                const unsigned int fb = __float_as_uint(d2);
                const unsigned int mm =
                    fb ^ ((unsigned int)((int)fb >> 31) | 0x80000000u);
                unsigned long long key =
                    ((unsigned long long)mm << 13) | (unsigned long long)j;
                key = (j == n) ? ~0ULL : key;
#pragma unroll
                for (int u = 0; u < KNN; ++u) {
                    const bool lt = key < md[u];
                    const unsigned long long lo = lt ? key : md[u];
                    key = lt ? md[u] : key;
                    md[u] = lo;
                }
            }
        }

        unsigned short* outp = knn_idx + ((size_t)b * NPTS + (n0 + t)) * KNN;
#pragma unroll
        for (int s = 0; s < KNN; ++s)
            outp[s] = (unsigned short)(md[s] & 8191u);
    }
}

// ---------------------------------------------------------------------------
// Features + MLP (unchanged from R5 — passed; revisit after knn).
// ---------------------------------------------------------------------------
__global__ __launch_bounds__(256) void feat_mlp_kernel(const float4* __restrict__ pts4,
                                                       const float* __restrict__ W1,
                                                       const float* __restrict__ b1,
                                                       const float* __restrict__ W2,
                                                       const float* __restrict__ b2,
                                                       const unsigned short* __restrict__ knn_idx,
                                                       float* __restrict__ out) {
    __shared__ float w1s[NF * 68];            // padded stride
    __shared__ float b1s[HID];
    __shared__ float w2s[HID * 3];
    __shared__ float b2s[3];
    __shared__ float fs[64][NF + 1];          // stride 77

    const int t = threadIdx.x;
    for (int idx = t; idx < NF * HID; idx += 256)
        w1s[(idx >> 6) * 68 + (idx & 63)] = W1[idx];
    if (t < HID) b1s[t] = b1[t];
    if (t < HID * 3) w2s[t] = W2[t];
    if (t < 3) b2s[t] = b2[t];

    const int pl   = t >> 2;                  // point slot 0..63
    const int subh = t & 1;                   // hidden half
    const int subf = (t >> 1) & 1;            // feature half
    const int gid = blockIdx.x * 64 + pl;     // 0..32767
    const int b = gid >> 13;
    const int n = gid & (NPTS - 1);
    const float4* pb = pts4 + b * NPTS;

    if ((t & 3) == 0) {                       // one lane per quad builds
        const float4 cq = pb[n];
        const float cx = cq.x, cy = cq.y, cz = cq.z;

        float nx[KNN], ny[KNN], nz[KNN];
        const unsigned short* ki = knn_idx + (size_t)gid * KNN;
#pragma unroll
        for (int k = 0; k < KNN; ++k) {
            const int j = ki[k];
            const float4 p = pb[j];
            nx[k] = p.x; ny[k] = p.y; nz[k] = p.z;
        }

        float* fr = fs[pl];
        fr[0] = cx; fr[1] = cy; fr[2] = cz;
#pragma unroll
        for (int k = 0; k < KNN; ++k) {
            fr[3 + 3 * k + 0] = nx[k];
            fr[3 + 3 * k + 1] = ny[k];
            fr[3 + 3 * k + 2] = nz[k];
        }
#pragma unroll
        for (int k = 0; k < KNN; ++k) {
            fr[33 + 3 * k + 0] = nx[k] - cx;
            fr[33 + 3 * k + 1] = ny[k] - cy;
            fr[33 + 3 * k + 2] = nz[k] - cz;
        }
#pragma unroll
        for (int k = 0; k < KNN; ++k) {
            const float rx = nx[k] - cx, ry = ny[k] - cy, rz = nz[k] - cz;
            fr[63 + k] = sqrtf(fmaf(rz, rz, fmaf(ry, ry, rx * rx)));
        }

        float mx = 0.f, my = 0.f, mz = 0.f;
#pragma unroll
        for (int k = 0; k < KNN; ++k) { mx += nx[k]; my += ny[k]; mz += nz[k]; }
        mx *= (1.0f / KNN); my *= (1.0f / KNN); mz *= (1.0f / KNN);
        float c00 = 0.f, c01 = 0.f, c02 = 0.f, c11 = 0.f, c12 = 0.f, c22 = 0.f;
#pragma unroll
        for (int k = 0; k < KNN; ++k) {
            const float ex = nx[k] - mx, ey = ny[k] - my, ez = nz[k] - mz;
            c00 = fmaf(ex, ex, c00); c01 = fmaf(ex, ey, c01); c02 = fmaf(ex, ez, c02);
            c11 = fmaf(ey, ey, c11); c12 = fmaf(ey, ez, c12); c22 = fmaf(ez, ez, c22);
        }
        const float sc = 1.0f / (KNN - 1);
        c00 *= sc; c01 *= sc; c02 *= sc; c11 *= sc; c12 *= sc; c22 *= sc;

        const double a00 = c00, a01 = c01, a02 = c02, a11 = c11, a12 = c12, a22 = c22;
        const double qd = (a00 + a11 + a22) / 3.0;
        const double p1 = a01 * a01 + a02 * a02 + a12 * a12;
        const double d00 = a00 - qd, d11 = a11 - qd, d22 = a22 - qd;
        const double p2 = d00 * d00 + d11 * d11 + d22 * d22 + 2.0 * p1;
        double l1, l2, l3;
        if (p2 < 1e-300) {
            l1 = l2 = l3 = qd;
        } else {
            const double p = sqrt(p2 / 6.0);
            const double inv = 1.0 / p;
            const double e00 = d00 * inv, e11 = d11 * inv, e22 = d22 * inv;
            const double e01 = a01 * inv, e02 = a02 * inv, e12 = a12 * inv;
            double detB = e00 * (e11 * e22 - e12 * e12)
                        - e01 * (e01 * e22 - e12 * e02)
                        + e02 * (e01 * e12 - e11 * e02);
            double r = 0.5 * detB;
            r = fmin(1.0, fmax(-1.0, r));
            const double phi = acos(r) / 3.0;
            l1 = qd + 2.0 * p * cos(phi);                          // largest
            l3 = qd + 2.0 * p * cos(phi + 2.0943951023931953);     // smallest
            l2 = 3.0 * qd - l1 - l3;
        }
        fr[73] = (float)((l1 - l2) / l1);
        fr[74] = (float)((l2 - l3) / l1);
        fr[75] = (float)(l3 / l1);
    }

    __syncthreads();   // weights + features visible

    const float* fr = fs[pl];
    const int f0 = subf * 38;

    float h[32];
#pragma unroll
    for (int j = 0; j < 32; ++j) h[j] = (subf == 0) ? b1s[subh * 32 + j] : 0.0f;

#pragma unroll 2
    for (int ff = 0; ff < 38; ++ff) {
        const int f = f0 + ff;
        const float v = fr[f];
        const float4* w4 = reinterpret_cast<const float4*>(w1s + f * 68 + subh * 32);
#pragma unroll
        for (int j4 = 0; j4 < 8; ++j4) {
            const float4 w = w4[j4];
            h[4 * j4 + 0] = fmaf(v, w.x, h[4 * j4 + 0]);
            h[4 * j4 + 1] = fmaf(v, w.y, h[4 * j4 + 1]);
            h[4 * j4 + 2] = fmaf(v, w.z, h[4 * j4 + 2]);
            h[4 * j4 + 3] = fmaf(v, w.w, h[4 * j4 + 3]);
        }
    }

    // combine feature halves (lanes differing in bit 1)
#pragma unroll
    for (int j = 0; j < 32; ++j) h[j] += __shfl_xor(h[j], 2, 64);

    float o0 = 0.f, o1 = 0.f, o2 = 0.f;
#pragma unroll
    for (int j = 0; j < 32; ++j) {
        const float r = fmaxf(h[j], 0.0f);
        const int jj = subh * 32 + j;
        o0 = fmaf(r, w2s[jj * 3 + 0], o0);
        o1 = fmaf(r, w2s[jj * 3 + 1], o1);
        o2 = fmaf(r, w2s[jj * 3 + 2], o2);
    }
    // combine hidden halves (lanes differing in bit 0)
    o0 += __shfl_xor(o0, 1, 64);
    o1 += __shfl_xor(o1, 1, 64);
    o2 += __shfl_xor(o2, 1, 64);

    if ((t & 3) == 0) {
        float* op = out + (size_t)gid * 3;
        op[0] = fmaxf(o0 + b2s[0], 0.0f);
        op[1] = fmaxf(o1 + b2s[1], 0.0f);
        op[2] = fmaxf(o2 + b2s[2], 0.0f);
    }
}

extern "C" void kernel_launch(void* const* d_in, const int* in_sizes, int n_in,
                              void* d_out, int out_size, void* d_ws, size_t ws_size,
                              hipStream_t stream) {
    const float* cloud = (const float*)d_in[0];   // [4,8192,3]
    const float* W1    = (const float*)d_in[1];   // [76,64]
    const float* b1    = (const float*)d_in[2];   // [64]
    const float* W2    = (const float*)d_in[3];   // [64,3]
    const float* b2    = (const float*)d_in[4];   // [3]
    float* out = (float*)d_out;                   // [4,8192,3]

    float4* pts4 = (float4*)d_ws;                                          // 512 KB
    unsigned short* knn = (unsigned short*)((char*)d_ws + 4 * NPTS * 16);  // 640 KB

    prep_kernel<<<dim3(128), dim3(256), 0, stream>>>(cloud, pts4);
    knn_kernel<<<dim3(512), dim3(1024), 0, stream>>>(pts4, knn);
    feat_mlp_kernel<<<dim3(512), dim3(256), 0, stream>>>(pts4, W1, b1, W2, b2, knn, out);
}

// Round 8
// 273.997 us; speedup vs baseline: 1.2696x; 1.2696x over previous
//
#include <hip/hip_runtime.h>
#include <math.h>

#define KNN    10
#define NPTS   8192
#define HID    64
#define NF     76
#define CHUNKS 16
#define CLEN   (NPTS / CHUNKS)   // 512
#define CAP    64                // pass-2 collection capacity per query
#define F32_INF __uint_as_float(0x7F800000u)

__device__ __forceinline__ float rl(float v, int lane) {
    return __int_as_float(__builtin_amdgcn_readlane(__float_as_int(v), lane));
}

// ---------------------------------------------------------------------------
// Prep: pts4[i] = (x, y, z, x^2+y^2+z^2)  (w chain identical to all rounds).
// ---------------------------------------------------------------------------
__global__ __launch_bounds__(256) void prep_kernel(const float* __restrict__ cloud,
                                                   float4* __restrict__ pts4) {
    const int i = blockIdx.x * 256 + threadIdx.x;      // 0..32767
    const float x = cloud[i * 3 + 0];
    const float y = cloud[i * 3 + 1];
    const float z = cloud[i * 3 + 2];
    pts4[i] = make_float4(x, y, z, fmaf(z, z, fmaf(y, y, x * x)));
}

// ---------------------------------------------------------------------------
// KNN — R6 selection math verbatim, candidate DELIVERY changed:
// R4-R7 evidence: duration pinned ~270-290us across 3x VALU reduction =>
// bound by the wave-uniform s_load candidate stream (scalar cache path).
// Now: each wave loads 64-candidate tiles coalesced into VGPRs (vector
// path), broadcasts each candidate with 4 v_readlane (VALU) -> zero SMEM
// in the scan loops. All computed float values bitwise-identical to R6:
//   pass1: v = fmaf(-2,dot,pw), chunk min (4 parallel accumulators);
//   tau  = qs + 11th-smallest-of-16-chunk-minima + 1e-3 (rank argument:
//          >=10 non-self chunk minima <= m_(11) => tau >= true 10th-NN);
//   pass2: d2 = fmaf(-2,dot,qs+pw) (exact R1-R5 expression), collect
//          (monotone(d2)<<13|j) for d2<=tau, j!=n; CAP 64 + fallback;
//   phase3: bubble top-10 of keys -> stable (d2 asc, idx asc) == jax top_k.
// Block = 1024 thr = 64 queries x 16 chunk-waves; grid 512.
// ---------------------------------------------------------------------------
__global__ __launch_bounds__(1024) void knn_kernel(const float4* __restrict__ pts4,
                                                   unsigned short* __restrict__ knn_idx) {
    __shared__ float pk[CHUNKS][64];                 // chunk v-minima, 4 KB
    __shared__ unsigned long long coll[CAP][65];     // [slot][query+pad], 33 KB
    __shared__ float tau[64];
    __shared__ int   cnt[64];

    const int t  = threadIdx.x;
    const int c  = t >> 6;                    // chunk 0..15 (wave id)
    const int ql = t & 63;                    // query slot == lane
    const int bx = blockIdx.x;                // 0..511
    const int b  = bx >> 7;                   // batch
    const int n0 = (bx & 127) * 64;
    const int n  = n0 + ql;                   // batch-local query index

    const float4* pb = pts4 + b * NPTS;
    const float4 q = pb[n];
    const float qx = q.x, qy = q.y, qz = q.z, qs = q.w;

    const int cb0 = __builtin_amdgcn_readfirstlane(c * CLEN);

    // ---------------- pass 1: chunk minimum of v = pw - 2*dot ----------------
    float vm0 = F32_INF, vm1 = F32_INF, vm2 = F32_INF, vm3 = F32_INF;
    float4 tp = pb[cb0 + ql];                 // tile 0 (coalesced vector load)
    for (int ti = 0; ti < CLEN / 64; ++ti) {  // 8 tiles
        const float4 tn = (ti < CLEN / 64 - 1) ? pb[cb0 + (ti + 1) * 64 + ql] : tp;
#pragma unroll
        for (int jj = 0; jj < 64; ++jj) {
            const float px = rl(tp.x, jj);
            const float py = rl(tp.y, jj);
            const float pz = rl(tp.z, jj);
            const float pw = rl(tp.w, jj);
            const float dot = fmaf(pz, qz, fmaf(py, qy, px * qx));
            const float v = fmaf(-2.0f, dot, pw);
            if ((jj & 3) == 0)      vm0 = fminf(vm0, v);
            else if ((jj & 3) == 1) vm1 = fminf(vm1, v);
            else if ((jj & 3) == 2) vm2 = fminf(vm2, v);
            else                    vm3 = fminf(vm3, v);
        }
        tp = tn;
    }
    pk[c][ql] = fminf(fminf(vm0, vm1), fminf(vm2, vm3));
    if (t < 64) cnt[t] = 0;
    __syncthreads();

    // wave 0: 11th smallest of the 16 chunk minima -> tau (d2 domain + margin)
    if (t < 64) {
        float md[KNN + 1];
#pragma unroll
        for (int s = 0; s <= KNN; ++s) md[s] = F32_INF;
#pragma unroll
        for (int cc = 0; cc < CHUNKS; ++cc) {
            float d = pk[cc][t];
#pragma unroll
            for (int u = 0; u <= KNN; ++u) {
                const float lo = fminf(md[u], d);
                d = fmaxf(md[u], d);
                md[u] = lo;
            }
        }
        tau[t] = qs + md[KNN] + 1e-3f;
    }
    __syncthreads();

    // ---------------- pass 2: exact collect (R1-R5-identical d2) ------------
    const float tq = tau[ql];
    tp = pb[cb0 + ql];
    for (int ti = 0; ti < CLEN / 64; ++ti) {
        const float4 tn = (ti < CLEN / 64 - 1) ? pb[cb0 + (ti + 1) * 64 + ql] : tp;
        const int jb = cb0 + ti * 64;
#pragma unroll
        for (int jj = 0; jj < 64; ++jj) {
            const float px = rl(tp.x, jj);
            const float py = rl(tp.y, jj);
            const float pz = rl(tp.z, jj);
            const float pw = rl(tp.w, jj);
            const float dot = fmaf(pz, qz, fmaf(py, qy, px * qx));
            const float d2 = fmaf(-2.0f, dot, qs + pw);
            const int j = jb + jj;
            if (__builtin_expect(d2 <= tq && j != n, 0)) {   // ~1.7% of iters
                const unsigned int fb = __float_as_uint(d2);
                const unsigned int m =
                    fb ^ ((unsigned int)((int)fb >> 31) | 0x80000000u);  // monotone
                const unsigned long long key =
                    ((unsigned long long)m << 13) | (unsigned long long)j;
                const int slot = atomicAdd(&cnt[ql], 1);
                if (slot < CAP) coll[slot][ql] = key;
            }
        }
        tp = tn;
    }
    __syncthreads();

    // ---------------- phase 3: exact stable top-10 ----------------
    if (t < 64) {
        const int m = cnt[t];
        int mc = m;
#pragma unroll
        for (int off = 1; off < 64; off <<= 1)
            mc = max(mc, __shfl_xor(mc, off, 64));
        mc = __builtin_amdgcn_readfirstlane(mc);

        unsigned long long md[KNN];
#pragma unroll
        for (int s = 0; s < KNN; ++s) md[s] = ~0ULL;

        if (mc <= CAP) {                       // normal path (uniform branch)
            for (int cc = 0; cc < mc; ++cc) {
                unsigned long long key = (cc < m) ? coll[cc][t] : ~0ULL;
#pragma unroll
                for (int u = 0; u < KNN; ++u) {
                    const bool lt = key < md[u];
                    const unsigned long long lo = lt ? key : md[u];
                    key = lt ? md[u] : key;
                    md[u] = lo;
                }
            }
        } else {
            // exact serial fallback (never expected): full rescan, branchless
            for (int j = 0; j < NPTS; ++j) {
                const float4 p = pb[j];
                const float dot = fmaf(p.z, qz, fmaf(p.y, qy, p.x * qx));
                const float d2 = fmaf(-2.0f, dot, qs + p.w);
                const unsigned int fb = __float_as_uint(d2);
                const unsigned int mm =
                    fb ^ ((unsigned int)((int)fb >> 31) | 0x80000000u);
                unsigned long long key =
                    ((unsigned long long)mm << 13) | (unsigned long long)j;
                key = (j == n) ? ~0ULL : key;
#pragma unroll
                for (int u = 0; u < KNN; ++u) {
                    const bool lt = key < md[u];
                    const unsigned long long lo = lt ? key : md[u];
                    key = lt ? md[u] : key;
                    md[u] = lo;
                }
            }
        }

        unsigned short* outp = knn_idx + ((size_t)b * NPTS + (n0 + t)) * KNN;
#pragma unroll
        for (int s = 0; s < KNN; ++s)
            outp[s] = (unsigned short)(md[s] & 8191u);
    }
}

// ---------------------------------------------------------------------------
// Features + MLP (unchanged — passed; revisit after knn).
// ---------------------------------------------------------------------------
__global__ __launch_bounds__(256) void feat_mlp_kernel(const float4* __restrict__ pts4,
                                                       const float* __restrict__ W1,
                                                       const float* __restrict__ b1,
                                                       const float* __restrict__ W2,
                                                       const float* __restrict__ b2,
                                                       const unsigned short* __restrict__ knn_idx,
                                                       float* __restrict__ out) {
    __shared__ float w1s[NF * 68];            // padded stride
    __shared__ float b1s[HID];
    __shared__ float w2s[HID * 3];
    __shared__ float b2s[3];
    __shared__ float fs[64][NF + 1];          // stride 77

    const int t = threadIdx.x;
    for (int idx = t; idx < NF * HID; idx += 256)
        w1s[(idx >> 6) * 68 + (idx & 63)] = W1[idx];
    if (t < HID) b1s[t] = b1[t];
    if (t < HID * 3) w2s[t] = W2[t];
    if (t < 3) b2s[t] = b2[t];

    const int pl   = t >> 2;                  // point slot 0..63
    const int subh = t & 1;                   // hidden half
    const int subf = (t >> 1) & 1;            // feature half
    const int gid = blockIdx.x * 64 + pl;     // 0..32767
    const int b = gid >> 13;
    const int n = gid & (NPTS - 1);
    const float4* pb = pts4 + b * NPTS;

    if ((t & 3) == 0) {                       // one lane per quad builds
        const float4 cq = pb[n];
        const float cx = cq.x, cy = cq.y, cz = cq.z;

        float nx[KNN], ny[KNN], nz[KNN];
        const unsigned short* ki = knn_idx + (size_t)gid * KNN;
#pragma unroll
        for (int k = 0; k < KNN; ++k) {
            const int j = ki[k];
            const float4 p = pb[j];
            nx[k] = p.x; ny[k] = p.y; nz[k] = p.z;
        }

        float* fr = fs[pl];
        fr[0] = cx; fr[1] = cy; fr[2] = cz;
#pragma unroll
        for (int k = 0; k < KNN; ++k) {
            fr[3 + 3 * k + 0] = nx[k];
            fr[3 + 3 * k + 1] = ny[k];
            fr[3 + 3 * k + 2] = nz[k];
        }
#pragma unroll
        for (int k = 0; k < KNN; ++k) {
            fr[33 + 3 * k + 0] = nx[k] - cx;
            fr[33 + 3 * k + 1] = ny[k] - cy;
            fr[33 + 3 * k + 2] = nz[k] - cz;
        }
#pragma unroll
        for (int k = 0; k < KNN; ++k) {
            const float rx = nx[k] - cx, ry = ny[k] - cy, rz = nz[k] - cz;
            fr[63 + k] = sqrtf(fmaf(rz, rz, fmaf(ry, ry, rx * rx)));
        }

        float mx = 0.f, my = 0.f, mz = 0.f;
#pragma unroll
        for (int k = 0; k < KNN; ++k) { mx += nx[k]; my += ny[k]; mz += nz[k]; }
        mx *= (1.0f / KNN); my *= (1.0f / KNN); mz *= (1.0f / KNN);
        float c00 = 0.f, c01 = 0.f, c02 = 0.f, c11 = 0.f, c12 = 0.f, c22 = 0.f;
#pragma unroll
        for (int k = 0; k < KNN; ++k) {
            const float ex = nx[k] - mx, ey = ny[k] - my, ez = nz[k] - mz;
            c00 = fmaf(ex, ex, c00); c01 = fmaf(ex, ey, c01); c02 = fmaf(ex, ez, c02);
            c11 = fmaf(ey, ey, c11); c12 = fmaf(ey, ez, c12); c22 = fmaf(ez, ez, c22);
        }
        const float sc = 1.0f / (KNN - 1);
        c00 *= sc; c01 *= sc; c02 *= sc; c11 *= sc; c12 *= sc; c22 *= sc;

        const double a00 = c00, a01 = c01, a02 = c02, a11 = c11, a12 = c12, a22 = c22;
        const double qd = (a00 + a11 + a22) / 3.0;
        const double p1 = a01 * a01 + a02 * a02 + a12 * a12;
        const double d00 = a00 - qd, d11 = a11 - qd, d22 = a22 - qd;
        const double p2 = d00 * d00 + d11 * d11 + d22 * d22 + 2.0 * p1;
        double l1, l2, l3;
        if (p2 < 1e-300) {
            l1 = l2 = l3 = qd;
        } else {
            const double p = sqrt(p2 / 6.0);
            const double inv = 1.0 / p;
            const double e00 = d00 * inv, e11 = d11 * inv, e22 = d22 * inv;
            const double e01 = a01 * inv, e02 = a02 * inv, e12 = a12 * inv;
            double detB = e00 * (e11 * e22 - e12 * e12)
                        - e01 * (e01 * e22 - e12 * e02)
                        + e02 * (e01 * e12 - e11 * e02);
            double r = 0.5 * detB;
            r = fmin(1.0, fmax(-1.0, r));
            const double phi = acos(r) / 3.0;
            l1 = qd + 2.0 * p * cos(phi);                          // largest
            l3 = qd + 2.0 * p * cos(phi + 2.0943951023931953);     // smallest
            l2 = 3.0 * qd - l1 - l3;
        }
        fr[73] = (float)((l1 - l2) / l1);
        fr[74] = (float)((l2 - l3) / l1);
        fr[75] = (float)(l3 / l1);
    }

    __syncthreads();   // weights + features visible

    const float* fr = fs[pl];
    const int f0 = subf * 38;

    float h[32];
#pragma unroll
    for (int j = 0; j < 32; ++j) h[j] = (subf == 0) ? b1s[subh * 32 + j] : 0.0f;

#pragma unroll 2
    for (int ff = 0; ff < 38; ++ff) {
        const int f = f0 + ff;
        const float v = fr[f];
        const float4* w4 = reinterpret_cast<const float4*>(w1s + f * 68 + subh * 32);
#pragma unroll
        for (int j4 = 0; j4 < 8; ++j4) {
            const float4 w = w4[j4];
            h[4 * j4 + 0] = fmaf(v, w.x, h[4 * j4 + 0]);
            h[4 * j4 + 1] = fmaf(v, w.y, h[4 * j4 + 1]);
            h[4 * j4 + 2] = fmaf(v, w.z, h[4 * j4 + 2]);
            h[4 * j4 + 3] = fmaf(v, w.w, h[4 * j4 + 3]);
        }
    }

    // combine feature halves (lanes differing in bit 1)
#pragma unroll
    for (int j = 0; j < 32; ++j) h[j] += __shfl_xor(h[j], 2, 64);

    float o0 = 0.f, o1 = 0.f, o2 = 0.f;
#pragma unroll
    for (int j = 0; j < 32; ++j) {
        const float r = fmaxf(h[j], 0.0f);
        const int jj = subh * 32 + j;
        o0 = fmaf(r, w2s[jj * 3 + 0], o0);
        o1 = fmaf(r, w2s[jj * 3 + 1], o1);
        o2 = fmaf(r, w2s[jj * 3 + 2], o2);
    }
    // combine hidden halves (lanes differing in bit 0)
    o0 += __shfl_xor(o0, 1, 64);
    o1 += __shfl_xor(o1, 1, 64);
    o2 += __shfl_xor(o2, 1, 64);

    if ((t & 3) == 0) {
        float* op = out + (size_t)gid * 3;
        op[0] = fmaxf(o0 + b2s[0], 0.0f);
        op[1] = fmaxf(o1 + b2s[1], 0.0f);
        op[2] = fmaxf(o2 + b2s[2], 0.0f);
    }
}

extern "C" void kernel_launch(void* const* d_in, const int* in_sizes, int n_in,
                              void* d_out, int out_size, void* d_ws, size_t ws_size,
                              hipStream_t stream) {
    const float* cloud = (const float*)d_in[0];   // [4,8192,3]
    const float* W1    = (const float*)d_in[1];   // [76,64]
    const float* b1    = (const float*)d_in[2];   // [64]
    const float* W2    = (const float*)d_in[3];   // [64,3]
    const float* b2    = (const float*)d_in[4];   // [3]
    float* out = (float*)d_out;                   // [4,8192,3]

    float4* pts4 = (float4*)d_ws;                                          // 512 KB
    unsigned short* knn = (unsigned short*)((char*)d_ws + 4 * NPTS * 16);  // 640 KB

    prep_kernel<<<dim3(128), dim3(256), 0, stream>>>(cloud, pts4);
    knn_kernel<<<dim3(512), dim3(1024), 0, stream>>>(pts4, knn);
    feat_mlp_kernel<<<dim3(512), dim3(256), 0, stream>>>(pts4, W1, b1, W2, b2, knn, out);
}

// Round 10
// 207.276 us; speedup vs baseline: 1.6783x; 1.3219x over previous
//
#include <hip/hip_runtime.h>
#include <math.h>

#define KNN    10
#define NPTS   8192
#define HID    64
#define NF     76
#define Q      16                // queries per wave
#define CAP    64                // pass-2 collection capacity per query
#define F32_INF __uint_as_float(0x7F800000u)

__device__ __forceinline__ float rl(float v, int lane) {
    return __int_as_float(__builtin_amdgcn_readlane(__float_as_int(v), lane));
}

// ---------------------------------------------------------------------------
// Prep: pts4[i] = (x, y, z, x^2+y^2+z^2)  (w chain identical to all rounds).
// ---------------------------------------------------------------------------
__global__ __launch_bounds__(256) void prep_kernel(const float* __restrict__ cloud,
                                                   float4* __restrict__ pts4) {
    const int i = blockIdx.x * 256 + threadIdx.x;      // 0..32767
    const float x = cloud[i * 3 + 0];
    const float y = cloud[i * 3 + 1];
    const float z = cloud[i * 3 + 2];
    pts4[i] = make_float4(x, y, z, fmaf(z, z, fmaf(y, y, x * x)));
}

// ---------------------------------------------------------------------------
// KNN, transposed scan (R9 structure) + R9 post-mortem fix:
// R9 failed marginally (absmax 3.9e-2): keys built from d2 = qs + v round
// differently than R1-R8's d2 = fmaf(-2,dot,qs+pw), flipping a near-tie
// neighbor pair. FIX: inside the rare hit branch, rebuild the key with the
// EXACT R8 expression fmaf(-2,dot,qs+pw) -> keys bitwise-identical to the
// 7x-validated selection. v-domain threshold unchanged (only gates a
// superset; 1e-3 margin >> ulp).
// Wave = Q=16 queries (SGPRs, uniform s_load) x 64 candidates/lane (float4
// VGPRs, coalesced). 5 VALU per (tile,query) hot path, zero broadcast ops.
// Pass 1: per-lane min of v = pw - 2*dot -> fold to 16 chunk minima/query
//   (2 shfl-min); taum = 11th-smallest + 1e-3 (v-domain rank bound: >=10
//   non-self chunk minima <= m_(11) => true 10th-NN v <= m_(11)).
// Pass 2: same body + compare; hits keyed ((mono(d2)<<13)|j), LDS atomic.
// Phase 3: per-query bubble top-10 -> stable (d2 asc, idx asc) == jax
//   top_k; exact serial fallback on overflow (never expected).
// Block = 256 thr = 4 waves x 16 queries; grid 512.
// ---------------------------------------------------------------------------
__global__ __launch_bounds__(256) void knn_kernel(const float4* __restrict__ pts4,
                                                  unsigned short* __restrict__ knn_idx) {
    __shared__ unsigned long long coll[CAP][65];   // [slot][local query+pad], 33 KB
    __shared__ float pk[4][Q][17];                 // folded chunk minima, 4.3 KB
    __shared__ int   cnt[64];

    const int t    = threadIdx.x;
    const int w    = t >> 6;                  // wave 0..3
    const int lane = t & 63;
    const int bx   = blockIdx.x;              // 0..511
    const int b    = bx >> 7;                 // batch
    const int n_base = (bx & 127) * 64 + w * Q;   // batch-local first query of wave
    const int lq_base = w * Q;                // block-local query base

    const float4* pb = pts4 + b * NPTS;

    if (lane < Q) cnt[lq_base + lane] = 0;    // wave-local rows, no barrier needed

    // Q queries into scalars (uniform address -> s_load)
    float qxs[Q], qys[Q], qzs[Q], qss[Q];
#pragma unroll
    for (int qq = 0; qq < Q; ++qq) {
        const float4 qv = pb[n_base + qq];
        qxs[qq] = qv.x; qys[qq] = qv.y; qzs[qq] = qv.z; qss[qq] = qv.w;
    }

    // ---------------- pass 1: per-lane chunk minima ----------------
    float vmin[Q];
#pragma unroll
    for (int qq = 0; qq < Q; ++qq) vmin[qq] = F32_INF;

    float4 cp = pb[lane];                     // coalesced vector load
    for (int ti = 0; ti < NPTS / 64; ++ti) {  // 128 tiles
        const float4 np = (ti < NPTS / 64 - 1) ? pb[(ti + 1) * 64 + lane] : cp;
#pragma unroll
        for (int qq = 0; qq < Q; ++qq) {
            const float dot = fmaf(cp.z, qzs[qq], fmaf(cp.y, qys[qq], cp.x * qxs[qq]));
            const float v = fmaf(-2.0f, dot, cp.w);
            vmin[qq] = fminf(vmin[qq], v);    // self included (rank arg handles it)
        }
        cp = np;
    }

    // fold 64 lane-minima -> 16 chunk minima per query, stash in LDS
#pragma unroll
    for (int qq = 0; qq < Q; ++qq) {
        float v = vmin[qq];
        v = fminf(v, __shfl_xor(v, 32, 64));
        v = fminf(v, __shfl_xor(v, 16, 64));
        if (lane < 16) pk[w][qq][lane] = v;
    }

    // lanes (lane&15)==qq: 11th smallest of 16 -> v-domain threshold
    float taum_v;
    {
        float md[KNN + 1];
#pragma unroll
        for (int s = 0; s <= KNN; ++s) md[s] = F32_INF;
        const int qsel = lane & 15;           // 4-way replicated (broadcast reads)
#pragma unroll
        for (int cc = 0; cc < 16; ++cc) {
            float d = pk[w][qsel][cc];
#pragma unroll
            for (int u = 0; u <= KNN; ++u) {
                const float lo = fminf(md[u], d);
                d = fmaxf(md[u], d);
                md[u] = lo;
            }
        }
        taum_v = md[KNN] + 1e-3f;
    }
    float taum[Q];
#pragma unroll
    for (int qq = 0; qq < Q; ++qq) taum[qq] = rl(taum_v, qq);   // -> SGPRs

    // ---------------- pass 2: collect hits (rare) ----------------
    float4 cp2 = pb[lane];
    int vj_rel = lane - n_base;               // j - n_base
    for (int ti = 0; ti < NPTS / 64; ++ti) {
        const float4 np = (ti < NPTS / 64 - 1) ? pb[(ti + 1) * 64 + lane] : cp2;
#pragma unroll
        for (int qq = 0; qq < Q; ++qq) {
            const float dot = fmaf(cp2.z, qzs[qq], fmaf(cp2.y, qys[qq], cp2.x * qxs[qq]));
            const float v = fmaf(-2.0f, dot, cp2.w);
            if (__builtin_expect(v <= taum[qq] && vj_rel != qq, 0)) {
                // KEY: bitwise-identical to R1-R8's d2 expression (the fix)
                const float d2 = fmaf(-2.0f, dot, qss[qq] + cp2.w);
                const unsigned int fb = __float_as_uint(d2);
                const unsigned int m =
                    fb ^ ((unsigned int)((int)fb >> 31) | 0x80000000u);  // monotone
                const int j = vj_rel + n_base;
                const unsigned long long key =
                    ((unsigned long long)m << 13) | (unsigned long long)(unsigned)j;
                const int slot = atomicAdd(&cnt[lq_base + qq], 1);
                if (slot < CAP) coll[slot][lq_base + qq] = key;
            }
        }
        cp2 = np; vj_rel += 64;
    }
    __syncthreads();

    // ---------------- phase 3: exact stable top-10 ----------------
    if (t < 64) {
        const int m = cnt[t];
        int mc = m;
#pragma unroll
        for (int off = 1; off < 64; off <<= 1)
            mc = max(mc, __shfl_xor(mc, off, 64));
        mc = __builtin_amdgcn_readfirstlane(mc);

        const int n = (bx & 127) * 64 + t;    // this lane's batch-local query

        unsigned long long md[KNN];
#pragma unroll
        for (int s = 0; s < KNN; ++s) md[s] = ~0ULL;

        if (mc <= CAP) {                       // normal path (uniform branch)
            for (int cc = 0; cc < mc; ++cc) {
                unsigned long long key = (cc < m) ? coll[cc][t] : ~0ULL;
#pragma unroll
                for (int u = 0; u < KNN; ++u) {
                    const bool lt = key < md[u];
                    const unsigned long long lo = lt ? key : md[u];
                    key = lt ? md[u] : key;
                    md[u] = lo;
                }
            }
        } else {
            // exact serial fallback (never expected): full rescan
            const float4 qv = pb[n];
            for (int j = 0; j < NPTS; ++j) {
                const float4 p = pb[j];
                const float dot = fmaf(p.z, qv.z, fmaf(p.y, qv.y, p.x * qv.x));
                const float d2 = fmaf(-2.0f, dot, qv.w + p.w);
                const unsigned int fb = __float_as_uint(d2);
                const unsigned int mm =
                    fb ^ ((unsigned int)((int)fb >> 31) | 0x80000000u);
                unsigned long long key =
                    ((unsigned long long)mm << 13) | (unsigned long long)j;
                key = (j == n) ? ~0ULL : key;
#pragma unroll
                for (int u = 0; u < KNN; ++u) {
                    const bool lt = key < md[u];
                    const unsigned long long lo = lt ? key : md[u];
                    key = lt ? md[u] : key;
                    md[u] = lo;
                }
            }
        }

        unsigned short* outp = knn_idx + ((size_t)b * NPTS + n) * KNN;
#pragma unroll
        for (int s = 0; s < KNN; ++s)
            outp[s] = (unsigned short)(md[s] & 8191u);
    }
}

// ---------------------------------------------------------------------------
// Features + MLP (unchanged — passed; next optimization target).
// ---------------------------------------------------------------------------
__global__ __launch_bounds__(256) void feat_mlp_kernel(const float4* __restrict__ pts4,
                                                       const float* __restrict__ W1,
                                                       const float* __restrict__ b1,
                                                       const float* __restrict__ W2,
                                                       const float* __restrict__ b2,
                                                       const unsigned short* __restrict__ knn_idx,
                                                       float* __restrict__ out) {
    __shared__ float w1s[NF * 68];            // padded stride
    __shared__ float b1s[HID];
    __shared__ float w2s[HID * 3];
    __shared__ float b2s[3];
    __shared__ float fs[64][NF + 1];          // stride 77

    const int t = threadIdx.x;
    for (int idx = t; idx < NF * HID; idx += 256)
        w1s[(idx >> 6) * 68 + (idx & 63)] = W1[idx];
    if (t < HID) b1s[t] = b1[t];
    if (t < HID * 3) w2s[t] = W2[t];
    if (t < 3) b2s[t] = b2[t];

    const int pl   = t >> 2;                  // point slot 0..63
    const int subh = t & 1;                   // hidden half
    const int subf = (t >> 1) & 1;            // feature half
    const int gid = blockIdx.x * 64 + pl;     // 0..32767
    const int b = gid >> 13;
    const int n = gid & (NPTS - 1);
    const float4* pb = pts4 + b * NPTS;

    if ((t & 3) == 0) {                       // one lane per quad builds
        const float4 cq = pb[n];
        const float cx = cq.x, cy = cq.y, cz = cq.z;

        float nx[KNN], ny[KNN], nz[KNN];
        const unsigned short* ki = knn_idx + (size_t)gid * KNN;
#pragma unroll
        for (int k = 0; k < KNN; ++k) {
            const int j = ki[k];
            const float4 p = pb[j];
            nx[k] = p.x; ny[k] = p.y; nz[k] = p.z;
        }

        float* fr = fs[pl];
        fr[0] = cx; fr[1] = cy; fr[2] = cz;
#pragma unroll
        for (int k = 0; k < KNN; ++k) {
            fr[3 + 3 * k + 0] = nx[k];
            fr[3 + 3 * k + 1] = ny[k];
            fr[3 + 3 * k + 2] = nz[k];
        }
#pragma unroll
        for (int k = 0; k < KNN; ++k) {
            fr[33 + 3 * k + 0] = nx[k] - cx;
            fr[33 + 3 * k + 1] = ny[k] - cy;
            fr[33 + 3 * k + 2] = nz[k] - cz;
        }
#pragma unroll
        for (int k = 0; k < KNN; ++k) {
            const float rx = nx[k] - cx, ry = ny[k] - cy, rz = nz[k] - cz;
            fr[63 + k] = sqrtf(fmaf(rz, rz, fmaf(ry, ry, rx * rx)));
        }

        float mx = 0.f, my = 0.f, mz = 0.f;
#pragma unroll
        for (int k = 0; k < KNN; ++k) { mx += nx[k]; my += ny[k]; mz += nz[k]; }
        mx *= (1.0f / KNN); my *= (1.0f / KNN); mz *= (1.0f / KNN);
        float c00 = 0.f, c01 = 0.f, c02 = 0.f, c11 = 0.f, c12 = 0.f, c22 = 0.f;
#pragma unroll
        for (int k = 0; k < KNN; ++k) {
            const float ex = nx[k] - mx, ey = ny[k] - my, ez = nz[k] - mz;
            c00 = fmaf(ex, ex, c00); c01 = fmaf(ex, ey, c01); c02 = fmaf(ex, ez, c02);
            c11 = fmaf(ey, ey, c11); c12 = fmaf(ey, ez, c12); c22 = fmaf(ez, ez, c22);
        }
        const float sc = 1.0f / (KNN - 1);
        c00 *= sc; c01 *= sc; c02 *= sc; c11 *= sc; c12 *= sc; c22 *= sc;

        const double a00 = c00, a01 = c01, a02 = c02, a11 = c11, a12 = c12, a22 = c22;
        const double qd = (a00 + a11 + a22) / 3.0;
        const double p1 = a01 * a01 + a02 * a02 + a12 * a12;
        const double d00 = a00 - qd, d11 = a11 - qd, d22 = a22 - qd;
        const double p2 = d00 * d00 + d11 * d11 + d22 * d22 + 2.0 * p1;
        double l1, l2, l3;
        if (p2 < 1e-300) {
            l1 = l2 = l3 = qd;
        } else {
            const double p = sqrt(p2 / 6.0);
            const double inv = 1.0 / p;
            const double e00 = d00 * inv, e11 = d11 * inv, e22 = d22 * inv;
            const double e01 = a01 * inv, e02 = a02 * inv, e12 = a12 * inv;
            double detB = e00 * (e11 * e22 - e12 * e12)
                        - e01 * (e01 * e22 - e12 * e02)
                        + e02 * (e01 * e12 - e11 * e02);
            double r = 0.5 * detB;
            r = fmin(1.0, fmax(-1.0, r));
            const double phi = acos(r) / 3.0;
            l1 = qd + 2.0 * p * cos(phi);                          // largest
            l3 = qd + 2.0 * p * cos(phi + 2.0943951023931953);     // smallest
            l2 = 3.0 * qd - l1 - l3;
        }
        fr[73] = (float)((l1 - l2) / l1);
        fr[74] = (float)((l2 - l3) / l1);
        fr[75] = (float)(l3 / l1);
    }

    __syncthreads();   // weights + features visible

    const float* fr = fs[pl];
    const int f0 = subf * 38;

    float h[32];
#pragma unroll
    for (int j = 0; j < 32; ++j) h[j] = (subf == 0) ? b1s[subh * 32 + j] : 0.0f;

#pragma unroll 2
    for (int ff = 0; ff < 38; ++ff) {
        const int f = f0 + ff;
        const float v = fr[f];
        const float4* w4 = reinterpret_cast<const float4*>(w1s + f * 68 + subh * 32);
#pragma unroll
        for (int j4 = 0; j4 < 8; ++j4) {
            const float4 w = w4[j4];
            h[4 * j4 + 0] = fmaf(v, w.x, h[4 * j4 + 0]);
            h[4 * j4 + 1] = fmaf(v, w.y, h[4 * j4 + 1]);
            h[4 * j4 + 2] = fmaf(v, w.z, h[4 * j4 + 2]);
            h[4 * j4 + 3] = fmaf(v, w.w, h[4 * j4 + 3]);
        }
    }

    // combine feature halves (lanes differing in bit 1)
#pragma unroll
    for (int j = 0; j < 32; ++j) h[j] += __shfl_xor(h[j], 2, 64);

    float o0 = 0.f, o1 = 0.f, o2 = 0.f;
#pragma unroll
    for (int j = 0; j < 32; ++j) {
        const float r = fmaxf(h[j], 0.0f);
        const int jj = subh * 32 + j;
        o0 = fmaf(r, w2s[jj * 3 + 0], o0);
        o1 = fmaf(r, w2s[jj * 3 + 1], o1);
        o2 = fmaf(r, w2s[jj * 3 + 2], o2);
    }
    // combine hidden halves (lanes differing in bit 0)
    o0 += __shfl_xor(o0, 1, 64);
    o1 += __shfl_xor(o1, 1, 64);
    o2 += __shfl_xor(o2, 1, 64);

    if ((t & 3) == 0) {
        float* op = out + (size_t)gid * 3;
        op[0] = fmaxf(o0 + b2s[0], 0.0f);
        op[1] = fmaxf(o1 + b2s[1], 0.0f);
        op[2] = fmaxf(o2 + b2s[2], 0.0f);
    }
}

extern "C" void kernel_launch(void* const* d_in, const int* in_sizes, int n_in,
                              void* d_out, int out_size, void* d_ws, size_t ws_size,
                              hipStream_t stream) {
    const float* cloud = (const float*)d_in[0];   // [4,8192,3]
    const float* W1    = (const float*)d_in[1];   // [76,64]
    const float* b1    = (const float*)d_in[2];   // [64]
    const float* W2    = (const float*)d_in[3];   // [64,3]
    const float* b2    = (const float*)d_in[4];   // [3]
    float* out = (float*)d_out;                   // [4,8192,3]

    float4* pts4 = (float4*)d_ws;                                          // 512 KB
    unsigned short* knn = (unsigned short*)((char*)d_ws + 4 * NPTS * 16);  // 640 KB

    prep_kernel<<<dim3(128), dim3(256), 0, stream>>>(cloud, pts4);
    knn_kernel<<<dim3(512), dim3(256), 0, stream>>>(pts4, knn);
    feat_mlp_kernel<<<dim3(512), dim3(256), 0, stream>>>(pts4, W1, b1, W2, b2, knn, out);
}

// Round 11
// 187.705 us; speedup vs baseline: 1.8533x; 1.1043x over previous
//
#include <hip/hip_runtime.h>
#include <math.h>

#define KNN    10
#define NPTS   8192
#define HID    64
#define NF     76
#define Q      16                // queries per wave
#define CAP    64                // pass-2 collection capacity per query
#define F32_INF __uint_as_float(0x7F800000u)

__device__ __forceinline__ float rl(float v, int lane) {
    return __int_as_float(__builtin_amdgcn_readlane(__float_as_int(v), lane));
}

// ---------------------------------------------------------------------------
// Prep: pts4[i] = (x, y, z, x^2+y^2+z^2)  (w chain identical to all rounds).
// ---------------------------------------------------------------------------
__global__ __launch_bounds__(256) void prep_kernel(const float* __restrict__ cloud,
                                                   float4* __restrict__ pts4) {
    const int i = blockIdx.x * 256 + threadIdx.x;      // 0..32767
    const float x = cloud[i * 3 + 0];
    const float y = cloud[i * 3 + 1];
    const float z = cloud[i * 3 + 2];
    pts4[i] = make_float4(x, y, z, fmaf(z, z, fmaf(y, y, x * x)));
}

// ---------------------------------------------------------------------------
// KNN, transposed scan. R10 post-mortem: occupancy was grid-capped at 20.8%
// (2048 waves = 2/SIMD). Now: 1024-thr block = 16 waves = 4 query-groups x
// 4 candidate-quarters (32 tiles each); grid 512 -> 8192 waves, 2 blocks/CU,
// 32 waves/CU nominal. Selection math & keys bitwise-identical to R10:
//   pass1: v = fmaf(-2,dot,pw), per-lane min over 32 cands, fold xor32/16 ->
//          16 chunk minima per (wave,query), chunk=128 cands; 64/query total.
//   tau  : 11th smallest of 64 chunk minima + 1e-3 (rank bound: >=10
//          non-self chunks among the 11 with min <= m_(11)).
//   pass2: same body + compare; hit branch rebuilds d2 = fmaf(-2,dot,qs+pw)
//          (exact R1-R10 expression), key = (mono(d2)<<13)|j, LDS atomic.
//          Append order across halves irrelevant: keys unique, fully sorted.
//   phase3: per-query bubble top-10 -> stable (d2 asc, idx asc) == jax
//          top_k; exact serial fallback on overflow (never expected).
// ---------------------------------------------------------------------------
__global__ __launch_bounds__(1024) void knn_kernel(const float4* __restrict__ pts4,
                                                   unsigned short* __restrict__ knn_idx) {
    __shared__ unsigned long long coll[CAP][65];   // [slot][block query+pad], 33 KB
    __shared__ float pk[16][Q][17];                // chunk minima, 17.4 KB
    __shared__ float tau_s[64];
    __shared__ int   cnt[64];

    const int t    = threadIdx.x;
    const int w    = t >> 6;                  // wave 0..15
    const int lane = t & 63;
    const int g    = w >> 2;                  // query group 0..3
    const int h    = w & 3;                   // candidate quarter 0..3
    const int bx   = blockIdx.x;              // 0..511
    const int b    = bx >> 7;                 // batch
    const int n_base = (bx & 127) * 64 + g * Q;   // batch-local first query of group
    const int lq_base = g * Q;                // block-local query base
    const int cb0 = h * (NPTS / 4);           // candidate base for this wave

    const float4* pb = pts4 + b * NPTS;

    if (t < 64) cnt[t] = 0;                   // visible after barrier 1

    // Q queries into scalars (uniform address -> s_load)
    float qxs[Q], qys[Q], qzs[Q], qss[Q];
#pragma unroll
    for (int qq = 0; qq < Q; ++qq) {
        const float4 qv = pb[n_base + qq];
        qxs[qq] = qv.x; qys[qq] = qv.y; qzs[qq] = qv.z; qss[qq] = qv.w;
    }

    // ---------------- pass 1: per-lane minima over this quarter ----------------
    float vmin[Q];
#pragma unroll
    for (int qq = 0; qq < Q; ++qq) vmin[qq] = F32_INF;

    float4 cp = pb[cb0 + lane];               // coalesced vector load
    for (int ti = 0; ti < NPTS / 4 / 64; ++ti) {  // 32 tiles
        const float4 np = (ti < NPTS / 4 / 64 - 1) ? pb[cb0 + (ti + 1) * 64 + lane] : cp;
#pragma unroll
        for (int qq = 0; qq < Q; ++qq) {
            const float dot = fmaf(cp.z, qzs[qq], fmaf(cp.y, qys[qq], cp.x * qxs[qq]));
            const float v = fmaf(-2.0f, dot, cp.w);
            vmin[qq] = fminf(vmin[qq], v);    // self included (rank arg handles it)
        }
        cp = np;
    }

    // fold 64 lane-minima -> 16 chunk minima (chunk = 128 cands), stash in LDS
#pragma unroll
    for (int qq = 0; qq < Q; ++qq) {
        float v = vmin[qq];
        v = fminf(v, __shfl_xor(v, 32, 64));
        v = fminf(v, __shfl_xor(v, 16, 64));
        if (lane < 16) pk[w][qq][lane] = v;
    }
    __syncthreads();                          // barrier 1: pk + cnt visible

    // h==0 waves: 11th smallest of 64 chunk minima -> tau for the group
    if (h == 0) {
        float md[KNN + 1];
#pragma unroll
        for (int s = 0; s <= KNN; ++s) md[s] = F32_INF;
        const int qsel = lane & 15;           // 4-way replicated
#pragma unroll
        for (int cc = 0; cc < 64; ++cc) {
            float d = pk[g * 4 + (cc >> 4)][qsel][cc & 15];
#pragma unroll
            for (int u = 0; u <= KNN; ++u) {
                const float lo = fminf(md[u], d);
                d = fmaxf(md[u], d);
                md[u] = lo;
            }
        }
        if (lane < 16) tau_s[lq_base + lane] = md[KNN] + 1e-3f;
    }
    __syncthreads();                          // barrier 2: tau visible

    float taum[Q];
    {
        const float tv = tau_s[lq_base + (lane & 15)];   // lane qq holds query qq's tau
#pragma unroll
        for (int qq = 0; qq < Q; ++qq) taum[qq] = rl(tv, qq);   // -> SGPRs
    }

    // ---------------- pass 2: collect hits (rare) ----------------
    float4 cp2 = pb[cb0 + lane];
    int vj_rel = cb0 + lane - n_base;         // j - n_base
    for (int ti = 0; ti < NPTS / 4 / 64; ++ti) {
        const float4 np = (ti < NPTS / 4 / 64 - 1) ? pb[cb0 + (ti + 1) * 64 + lane] : cp2;
#pragma unroll
        for (int qq = 0; qq < Q; ++qq) {
            const float dot = fmaf(cp2.z, qzs[qq], fmaf(cp2.y, qys[qq], cp2.x * qxs[qq]));
            const float v = fmaf(-2.0f, dot, cp2.w);
            if (__builtin_expect(v <= taum[qq] && vj_rel != qq, 0)) {
                // KEY: bitwise-identical to R1-R10's d2 expression
                const float d2 = fmaf(-2.0f, dot, qss[qq] + cp2.w);
                const unsigned int fb = __float_as_uint(d2);
                const unsigned int m =
                    fb ^ ((unsigned int)((int)fb >> 31) | 0x80000000u);  // monotone
                const int j = vj_rel + n_base;
                const unsigned long long key =
                    ((unsigned long long)m << 13) | (unsigned long long)(unsigned)j;
                const int slot = atomicAdd(&cnt[lq_base + qq], 1);
                if (slot < CAP) coll[slot][lq_base + qq] = key;
            }
        }
        cp2 = np; vj_rel += 64;
    }
    __syncthreads();

    // ---------------- phase 3: exact stable top-10 (wave 0) ----------------
    if (t < 64) {
        const int m = cnt[t];
        int mc = m;
#pragma unroll
        for (int off = 1; off < 64; off <<= 1)
            mc = max(mc, __shfl_xor(mc, off, 64));
        mc = __builtin_amdgcn_readfirstlane(mc);

        const int n = (bx & 127) * 64 + t;    // this lane's batch-local query

        unsigned long long md[KNN];
#pragma unroll
        for (int s = 0; s < KNN; ++s) md[s] = ~0ULL;

        if (mc <= CAP) {                       // normal path (uniform branch)
            for (int cc = 0; cc < mc; ++cc) {
                unsigned long long key = (cc < m) ? coll[cc][t] : ~0ULL;
#pragma unroll
                for (int u = 0; u < KNN; ++u) {
                    const bool lt = key < md[u];
                    const unsigned long long lo = lt ? key : md[u];
                    key = lt ? md[u] : key;
                    md[u] = lo;
                }
            }
        } else {
            // exact serial fallback (never expected): full rescan
            const float4 qv = pb[n];
            for (int j = 0; j < NPTS; ++j) {
                const float4 p = pb[j];
                const float dot = fmaf(p.z, qv.z, fmaf(p.y, qv.y, p.x * qv.x));
                const float d2 = fmaf(-2.0f, dot, qv.w + p.w);
                const unsigned int fb = __float_as_uint(d2);
                const unsigned int mm =
                    fb ^ ((unsigned int)((int)fb >> 31) | 0x80000000u);
                unsigned long long key =
                    ((unsigned long long)mm << 13) | (unsigned long long)j;
                key = (j == n) ? ~0ULL : key;
#pragma unroll
                for (int u = 0; u < KNN; ++u) {
                    const bool lt = key < md[u];
                    const unsigned long long lo = lt ? key : md[u];
                    key = lt ? md[u] : key;
                    md[u] = lo;
                }
            }
        }

        unsigned short* outp = knn_idx + ((size_t)b * NPTS + n) * KNN;
#pragma unroll
        for (int s = 0; s < KNN; ++s)
            outp[s] = (unsigned short)(md[s] & 8191u);
    }
}

// ---------------------------------------------------------------------------
// Features + MLP. Change vs R10: fp32 eigen closed-form (acosf/cosf at
// near-HW rate) replacing fp64 libm transcendentals — the dominant
// serialized-latency term of this latency-bound kernel. Reference eigvalsh
// is fp32 LAPACK; error budget ~1e-3 << 2.89e-2 threshold.
// ---------------------------------------------------------------------------
__global__ __launch_bounds__(256) void feat_mlp_kernel(const float4* __restrict__ pts4,
                                                       const float* __restrict__ W1,
                                                       const float* __restrict__ b1,
                                                       const float* __restrict__ W2,
                                                       const float* __restrict__ b2,
                                                       const unsigned short* __restrict__ knn_idx,
                                                       float* __restrict__ out) {
    __shared__ float w1s[NF * 68];            // padded stride
    __shared__ float b1s[HID];
    __shared__ float w2s[HID * 3];
    __shared__ float b2s[3];
    __shared__ float fs[64][NF + 1];          // stride 77

    const int t = threadIdx.x;
    for (int idx = t; idx < NF * HID; idx += 256)
        w1s[(idx >> 6) * 68 + (idx & 63)] = W1[idx];
    if (t < HID) b1s[t] = b1[t];
    if (t < HID * 3) w2s[t] = W2[t];
    if (t < 3) b2s[t] = b2[t];

    const int pl   = t >> 2;                  // point slot 0..63
    const int subh = t & 1;                   // hidden half
    const int subf = (t >> 1) & 1;            // feature half
    const int gid = blockIdx.x * 64 + pl;     // 0..32767
    const int b = gid >> 13;
    const int n = gid & (NPTS - 1);
    const float4* pb = pts4 + b * NPTS;

    if ((t & 3) == 0) {                       // one lane per quad builds
        const float4 cq = pb[n];
        const float cx = cq.x, cy = cq.y, cz = cq.z;

        float nx[KNN], ny[KNN], nz[KNN];
        const unsigned short* ki = knn_idx + (size_t)gid * KNN;
#pragma unroll
        for (int k = 0; k < KNN; ++k) {
            const int j = ki[k];
            const float4 p = pb[j];
            nx[k] = p.x; ny[k] = p.y; nz[k] = p.z;
        }

        float* fr = fs[pl];
        fr[0] = cx; fr[1] = cy; fr[2] = cz;
#pragma unroll
        for (int k = 0; k < KNN; ++k) {
            fr[3 + 3 * k + 0] = nx[k];
            fr[3 + 3 * k + 1] = ny[k];
            fr[3 + 3 * k + 2] = nz[k];
        }
#pragma unroll
        for (int k = 0; k < KNN; ++k) {
            fr[33 + 3 * k + 0] = nx[k] - cx;
            fr[33 + 3 * k + 1] = ny[k] - cy;
            fr[33 + 3 * k + 2] = nz[k] - cz;
        }
#pragma unroll
        for (int k = 0; k < KNN; ++k) {
            const float rx = nx[k] - cx, ry = ny[k] - cy, rz = nz[k] - cz;
            fr[63 + k] = sqrtf(fmaf(rz, rz, fmaf(ry, ry, rx * rx)));
        }

        float mx = 0.f, my = 0.f, mz = 0.f;
#pragma unroll
        for (int k = 0; k < KNN; ++k) { mx += nx[k]; my += ny[k]; mz += nz[k]; }
        mx *= (1.0f / KNN); my *= (1.0f / KNN); mz *= (1.0f / KNN);
        float c00 = 0.f, c01 = 0.f, c02 = 0.f, c11 = 0.f, c12 = 0.f, c22 = 0.f;
#pragma unroll
        for (int k = 0; k < KNN; ++k) {
            const float ex = nx[k] - mx, ey = ny[k] - my, ez = nz[k] - mz;
            c00 = fmaf(ex, ex, c00); c01 = fmaf(ex, ey, c01); c02 = fmaf(ex, ez, c02);
            c11 = fmaf(ey, ey, c11); c12 = fmaf(ey, ez, c12); c22 = fmaf(ez, ez, c22);
        }
        const float sc = 1.0f / (KNN - 1);
        c00 *= sc; c01 *= sc; c02 *= sc; c11 *= sc; c12 *= sc; c22 *= sc;

        // fp32 closed-form symmetric 3x3 eigenvalues
        const float qd = (c00 + c11 + c22) * (1.0f / 3.0f);
        const float pp1 = c01 * c01 + c02 * c02 + c12 * c12;
        const float d00 = c00 - qd, d11 = c11 - qd, d22 = c22 - qd;
        const float p2 = d00 * d00 + d11 * d11 + d22 * d22 + 2.0f * pp1;
        float l1, l2, l3;
        if (p2 < 1e-30f) {
            l1 = l2 = l3 = qd;
        } else {
            const float p = sqrtf(p2 * (1.0f / 6.0f));
            const float inv = 1.0f / p;
            const float e00 = d00 * inv, e11 = d11 * inv, e22 = d22 * inv;
            const float e01 = c01 * inv, e02 = c02 * inv, e12 = c12 * inv;
            float detB = e00 * (e11 * e22 - e12 * e12)
                       - e01 * (e01 * e22 - e12 * e02)
                       + e02 * (e01 * e12 - e11 * e02);
            float r = 0.5f * detB;
            r = fminf(1.0f, fmaxf(-1.0f, r));
            const float phi = acosf(r) * (1.0f / 3.0f);
            l1 = qd + 2.0f * p * __cosf(phi);                          // largest
            l3 = qd + 2.0f * p * __cosf(phi + 2.0943951023931953f);    // smallest
            l2 = 3.0f * qd - l1 - l3;
        }
        fr[73] = (l1 - l2) / l1;
        fr[74] = (l2 - l3) / l1;
        fr[75] = l3 / l1;
    }

    __syncthreads();   // weights + features visible

    const float* fr = fs[pl];
    const int f0 = subf * 38;

    float h[32];
#pragma unroll
    for (int j = 0; j < 32; ++j) h[j] = (subf == 0) ? b1s[subh * 32 + j] : 0.0f;

#pragma unroll 2
    for (int ff = 0; ff < 38; ++ff) {
        const int f = f0 + ff;
        const float v = fr[f];
        const float4* w4 = reinterpret_cast<const float4*>(w1s + f * 68 + subh * 32);
#pragma unroll
        for (int j4 = 0; j4 < 8; ++j4) {
            const float4 w = w4[j4];
            h[4 * j4 + 0] = fmaf(v, w.x, h[4 * j4 + 0]);
            h[4 * j4 + 1] = fmaf(v, w.y, h[4 * j4 + 1]);
            h[4 * j4 + 2] = fmaf(v, w.z, h[4 * j4 + 2]);
            h[4 * j4 + 3] = fmaf(v, w.w, h[4 * j4 + 3]);
        }
    }

    // combine feature halves (lanes differing in bit 1)
#pragma unroll
    for (int j = 0; j < 32; ++j) h[j] += __shfl_xor(h[j], 2, 64);

    float o0 = 0.f, o1 = 0.f, o2 = 0.f;
#pragma unroll
    for (int j = 0; j < 32; ++j) {
        const float r = fmaxf(h[j], 0.0f);
        const int jj = subh * 32 + j;
        o0 = fmaf(r, w2s[jj * 3 + 0], o0);
        o1 = fmaf(r, w2s[jj * 3 + 1], o1);
        o2 = fmaf(r, w2s[jj * 3 + 2], o2);
    }
    // combine hidden halves (lanes differing in bit 0)
    o0 += __shfl_xor(o0, 1, 64);
    o1 += __shfl_xor(o1, 1, 64);
    o2 += __shfl_xor(o2, 1, 64);

    if ((t & 3) == 0) {
        float* op = out + (size_t)gid * 3;
        op[0] = fmaxf(o0 + b2s[0], 0.0f);
        op[1] = fmaxf(o1 + b2s[1], 0.0f);
        op[2] = fmaxf(o2 + b2s[2], 0.0f);
    }
}

extern "C" void kernel_launch(void* const* d_in, const int* in_sizes, int n_in,
                              void* d_out, int out_size, void* d_ws, size_t ws_size,
                              hipStream_t stream) {
    const float* cloud = (const float*)d_in[0];   // [4,8192,3]
    const float* W1    = (const float*)d_in[1];   // [76,64]
    const float* b1    = (const float*)d_in[2];   // [64]
    const float* W2    = (const float*)d_in[3];   // [64,3]
    const float* b2    = (const float*)d_in[4];   // [3]
    float* out = (float*)d_out;                   // [4,8192,3]

    float4* pts4 = (float4*)d_ws;                                          // 512 KB
    unsigned short* knn = (unsigned short*)((char*)d_ws + 4 * NPTS * 16);  // 640 KB

    prep_kernel<<<dim3(128), dim3(256), 0, stream>>>(cloud, pts4);
    knn_kernel<<<dim3(512), dim3(1024), 0, stream>>>(pts4, knn);
    feat_mlp_kernel<<<dim3(512), dim3(256), 0, stream>>>(pts4, W1, b1, W2, b2, knn, out);
}

// Round 12
// 183.238 us; speedup vs baseline: 1.8985x; 1.0244x over previous
//
#include <hip/hip_runtime.h>
#include <math.h>

#define KNN    10
#define NPTS   8192
#define HID    64
#define NF     76
#define Q      16                // queries per wave
#define CAP    64                // pass-2 collection capacity per query
#define F32_INF __uint_as_float(0x7F800000u)

__device__ __forceinline__ float rl(float v, int lane) {
    return __int_as_float(__builtin_amdgcn_readlane(__float_as_int(v), lane));
}

// ---------------------------------------------------------------------------
// Prep: pts4[i] = (x, y, z, x^2+y^2+z^2)  (w chain identical to all rounds).
// ---------------------------------------------------------------------------
__global__ __launch_bounds__(256) void prep_kernel(const float* __restrict__ cloud,
                                                   float4* __restrict__ pts4) {
    const int i = blockIdx.x * 256 + threadIdx.x;      // 0..32767
    const float x = cloud[i * 3 + 0];
    const float y = cloud[i * 3 + 1];
    const float z = cloud[i * 3 + 2];
    pts4[i] = make_float4(x, y, z, fmaf(z, z, fmaf(y, y, x * x)));
}

// ---------------------------------------------------------------------------
// KNN, transposed scan. R12 changes vs R11 (both passes):
//  (1) scan body 5 -> 4 ops: fold -2 into candidate coords once per tile
//      (a2x=-2*px etc, 3 ops amortized over 16 queries);
//      v' = fmaf(a2x,qx, fmaf(a2y,qy, fmaf(a2z,qz, pw))) — SAME expression
//      in pass 1 and pass 2 (consistent ordering; rank bound in v'-domain,
//      1e-3 margin >> ~1e-5 v'<->key-order discrepancy).
//  (2) pass 2 drops the per-pair self compare: self is collected (its v' is
//      ~global min, always passes), phase 3 bubbles TOP-11 and filters
//      idx==n, outputs first 10. >=10 non-self collected by the rank bound,
//      so 10 outputs always exist.
//  Hit branch recovers px = -0.5f*a2x (bitwise-exact pow2 scale) and builds
//  the key from d2 = fmaf(-2,dot,qs+pw), dot = fmaf(pz,qz,fmaf(py,qy,px*qx))
//  — bitwise-identical to R1-R11 keys => selection unchanged.
// Block = 1024 thr = 16 waves = 4 query-groups x 4 candidate-quarters.
// ---------------------------------------------------------------------------
__global__ __launch_bounds__(1024) void knn_kernel(const float4* __restrict__ pts4,
                                                   unsigned short* __restrict__ knn_idx) {
    __shared__ unsigned long long coll[CAP][65];   // [slot][block query+pad], 33 KB
    __shared__ float pk[16][Q][17];                // chunk minima, 17.4 KB
    __shared__ float tau_s[64];
    __shared__ int   cnt[64];

    const int t    = threadIdx.x;
    const int w    = t >> 6;                  // wave 0..15
    const int lane = t & 63;
    const int g    = w >> 2;                  // query group 0..3
    const int h    = w & 3;                   // candidate quarter 0..3
    const int bx   = blockIdx.x;              // 0..511
    const int b    = bx >> 7;                 // batch
    const int n_base = (bx & 127) * 64 + g * Q;   // batch-local first query of group
    const int lq_base = g * Q;                // block-local query base
    const int cb0 = h * (NPTS / 4);           // candidate base for this wave

    const float4* pb = pts4 + b * NPTS;

    if (t < 64) cnt[t] = 0;                   // visible after barrier 1

    // Q queries into scalars (uniform address -> s_load)
    float qxs[Q], qys[Q], qzs[Q], qss[Q];
#pragma unroll
    for (int qq = 0; qq < Q; ++qq) {
        const float4 qv = pb[n_base + qq];
        qxs[qq] = qv.x; qys[qq] = qv.y; qzs[qq] = qv.z; qss[qq] = qv.w;
    }

    // ---------------- pass 1: per-lane minima over this quarter ----------------
    float vmin[Q];
#pragma unroll
    for (int qq = 0; qq < Q; ++qq) vmin[qq] = F32_INF;

    float4 cp = pb[cb0 + lane];               // coalesced vector load
    for (int ti = 0; ti < NPTS / 4 / 64; ++ti) {  // 32 tiles
        const float4 np = (ti < NPTS / 4 / 64 - 1) ? pb[cb0 + (ti + 1) * 64 + lane] : cp;
        const float a2x = -2.0f * cp.x;       // once per tile, amortized /16
        const float a2y = -2.0f * cp.y;
        const float a2z = -2.0f * cp.z;
        const float aw  = cp.w;
#pragma unroll
        for (int qq = 0; qq < Q; ++qq) {
            const float v = fmaf(a2x, qxs[qq], fmaf(a2y, qys[qq], fmaf(a2z, qzs[qq], aw)));
            vmin[qq] = fminf(vmin[qq], v);    // self included (rank arg handles it)
        }
        cp = np;
    }

    // fold 64 lane-minima -> 16 chunk minima (chunk = 128 cands), stash in LDS
#pragma unroll
    for (int qq = 0; qq < Q; ++qq) {
        float v = vmin[qq];
        v = fminf(v, __shfl_xor(v, 32, 64));
        v = fminf(v, __shfl_xor(v, 16, 64));
        if (lane < 16) pk[w][qq][lane] = v;
    }
    __syncthreads();                          // barrier 1: pk + cnt visible

    // h==0 waves: 11th smallest of 64 chunk minima -> tau for the group
    if (h == 0) {
        float md[KNN + 1];
#pragma unroll
        for (int s = 0; s <= KNN; ++s) md[s] = F32_INF;
        const int qsel = lane & 15;           // 4-way replicated
#pragma unroll
        for (int cc = 0; cc < 64; ++cc) {
            float d = pk[g * 4 + (cc >> 4)][qsel][cc & 15];
#pragma unroll
            for (int u = 0; u <= KNN; ++u) {
                const float lo = fminf(md[u], d);
                d = fmaxf(md[u], d);
                md[u] = lo;
            }
        }
        if (lane < 16) tau_s[lq_base + lane] = md[KNN] + 1e-3f;
    }
    __syncthreads();                          // barrier 2: tau visible

    float taum[Q];
    {
        const float tv = tau_s[lq_base + (lane & 15)];   // lane qq holds query qq's tau
#pragma unroll
        for (int qq = 0; qq < Q; ++qq) taum[qq] = rl(tv, qq);   // -> SGPRs
    }

    // ---------------- pass 2: collect hits incl. self (rare) ----------------
    float4 cp2 = pb[cb0 + lane];
    int jcur = cb0 + lane;                    // this lane's candidate index
    for (int ti = 0; ti < NPTS / 4 / 64; ++ti) {
        const float4 np = (ti < NPTS / 4 / 64 - 1) ? pb[cb0 + (ti + 1) * 64 + lane] : cp2;
        const float a2x = -2.0f * cp2.x;
        const float a2y = -2.0f * cp2.y;
        const float a2z = -2.0f * cp2.z;
        const float aw  = cp2.w;
#pragma unroll
        for (int qq = 0; qq < Q; ++qq) {
            const float v = fmaf(a2x, qxs[qq], fmaf(a2y, qys[qq], fmaf(a2z, qzs[qq], aw)));
            if (__builtin_expect(v <= taum[qq], 0)) {
                // recover originals bitwise (pow2 scale), rebuild R1-R11 key
                const float px = -0.5f * a2x;
                const float py = -0.5f * a2y;
                const float pz = -0.5f * a2z;
                const float dot = fmaf(pz, qzs[qq], fmaf(py, qys[qq], px * qxs[qq]));
                const float d2 = fmaf(-2.0f, dot, qss[qq] + aw);
                const unsigned int fb = __float_as_uint(d2);
                const unsigned int m =
                    fb ^ ((unsigned int)((int)fb >> 31) | 0x80000000u);  // monotone
                const unsigned long long key =
                    ((unsigned long long)m << 13) | (unsigned long long)(unsigned)jcur;
                const int slot = atomicAdd(&cnt[lq_base + qq], 1);
                if (slot < CAP) coll[slot][lq_base + qq] = key;
            }
        }
        cp2 = np; jcur += 64;
    }
    __syncthreads();

    // ---------------- phase 3: top-11 bubble, filter self by index ----------
    if (t < 64) {
        const int m = cnt[t];
        int mc = m;
#pragma unroll
        for (int off = 1; off < 64; off <<= 1)
            mc = max(mc, __shfl_xor(mc, off, 64));
        mc = __builtin_amdgcn_readfirstlane(mc);

        const int n = (bx & 127) * 64 + t;    // this lane's batch-local query

        unsigned long long md[KNN + 1];
#pragma unroll
        for (int s = 0; s <= KNN; ++s) md[s] = ~0ULL;

        if (mc <= CAP) {                       // normal path (uniform branch)
            for (int cc = 0; cc < mc; ++cc) {
                unsigned long long key = (cc < m) ? coll[cc][t] : ~0ULL;
#pragma unroll
                for (int u = 0; u <= KNN; ++u) {
                    const bool lt = key < md[u];
                    const unsigned long long lo = lt ? key : md[u];
                    key = lt ? md[u] : key;
                    md[u] = lo;
                }
            }
        } else {
            // exact serial fallback (never expected): full rescan, self excluded
            const float4 qv = pb[n];
            for (int j = 0; j < NPTS; ++j) {
                const float4 p = pb[j];
                const float dot = fmaf(p.z, qv.z, fmaf(p.y, qv.y, p.x * qv.x));
                const float d2 = fmaf(-2.0f, dot, qv.w + p.w);
                const unsigned int fb = __float_as_uint(d2);
                const unsigned int mm =
                    fb ^ ((unsigned int)((int)fb >> 31) | 0x80000000u);
                unsigned long long key =
                    ((unsigned long long)mm << 13) | (unsigned long long)j;
                key = (j == n) ? ~0ULL : key;
#pragma unroll
                for (int u = 0; u <= KNN; ++u) {
                    const bool lt = key < md[u];
                    const unsigned long long lo = lt ? key : md[u];
                    key = lt ? md[u] : key;
                    md[u] = lo;
                }
            }
        }

        unsigned short* outp = knn_idx + ((size_t)b * NPTS + n) * KNN;
        int outc = 0;
#pragma unroll
        for (int u = 0; u <= KNN; ++u) {
            const int idx = (int)(md[u] & 8191u);
            if (outc < KNN && idx != n) outp[outc++] = (unsigned short)idx;
        }
    }
}

// ---------------------------------------------------------------------------
// Features + MLP (unchanged from R11 — fp32 eigen verified, absmax held).
// ---------------------------------------------------------------------------
__global__ __launch_bounds__(256) void feat_mlp_kernel(const float4* __restrict__ pts4,
                                                       const float* __restrict__ W1,
                                                       const float* __restrict__ b1,
                                                       const float* __restrict__ W2,
                                                       const float* __restrict__ b2,
                                                       const unsigned short* __restrict__ knn_idx,
                                                       float* __restrict__ out) {
    __shared__ float w1s[NF * 68];            // padded stride
    __shared__ float b1s[HID];
    __shared__ float w2s[HID * 3];
    __shared__ float b2s[3];
    __shared__ float fs[64][NF + 1];          // stride 77

    const int t = threadIdx.x;
    for (int idx = t; idx < NF * HID; idx += 256)
        w1s[(idx >> 6) * 68 + (idx & 63)] = W1[idx];
    if (t < HID) b1s[t] = b1[t];
    if (t < HID * 3) w2s[t] = W2[t];
    if (t < 3) b2s[t] = b2[t];

    const int pl   = t >> 2;                  // point slot 0..63
    const int subh = t & 1;                   // hidden half
    const int subf = (t >> 1) & 1;            // feature half
    const int gid = blockIdx.x * 64 + pl;     // 0..32767
    const int b = gid >> 13;
    const int n = gid & (NPTS - 1);
    const float4* pb = pts4 + b * NPTS;

    if ((t & 3) == 0) {                       // one lane per quad builds
        const float4 cq = pb[n];
        const float cx = cq.x, cy = cq.y, cz = cq.z;

        float nx[KNN], ny[KNN], nz[KNN];
        const unsigned short* ki = knn_idx + (size_t)gid * KNN;
#pragma unroll
        for (int k = 0; k < KNN; ++k) {
            const int j = ki[k];
            const float4 p = pb[j];
            nx[k] = p.x; ny[k] = p.y; nz[k] = p.z;
        }

        float* fr = fs[pl];
        fr[0] = cx; fr[1] = cy; fr[2] = cz;
#pragma unroll
        for (int k = 0; k < KNN; ++k) {
            fr[3 + 3 * k + 0] = nx[k];
            fr[3 + 3 * k + 1] = ny[k];
            fr[3 + 3 * k + 2] = nz[k];
        }
#pragma unroll
        for (int k = 0; k < KNN; ++k) {
            fr[33 + 3 * k + 0] = nx[k] - cx;
            fr[33 + 3 * k + 1] = ny[k] - cy;
            fr[33 + 3 * k + 2] = nz[k] - cz;
        }
#pragma unroll
        for (int k = 0; k < KNN; ++k) {
            const float rx = nx[k] - cx, ry = ny[k] - cy, rz = nz[k] - cz;
            fr[63 + k] = sqrtf(fmaf(rz, rz, fmaf(ry, ry, rx * rx)));
        }

        float mx = 0.f, my = 0.f, mz = 0.f;
#pragma unroll
        for (int k = 0; k < KNN; ++k) { mx += nx[k]; my += ny[k]; mz += nz[k]; }
        mx *= (1.0f / KNN); my *= (1.0f / KNN); mz *= (1.0f / KNN);
        float c00 = 0.f, c01 = 0.f, c02 = 0.f, c11 = 0.f, c12 = 0.f, c22 = 0.f;
#pragma unroll
        for (int k = 0; k < KNN; ++k) {
            const float ex = nx[k] - mx, ey = ny[k] - my, ez = nz[k] - mz;
            c00 = fmaf(ex, ex, c00); c01 = fmaf(ex, ey, c01); c02 = fmaf(ex, ez, c02);
            c11 = fmaf(ey, ey, c11); c12 = fmaf(ey, ez, c12); c22 = fmaf(ez, ez, c22);
        }
        const float sc = 1.0f / (KNN - 1);
        c00 *= sc; c01 *= sc; c02 *= sc; c11 *= sc; c12 *= sc; c22 *= sc;

        // fp32 closed-form symmetric 3x3 eigenvalues
        const float qd = (c00 + c11 + c22) * (1.0f / 3.0f);
        const float pp1 = c01 * c01 + c02 * c02 + c12 * c12;
        const float d00 = c00 - qd, d11 = c11 - qd, d22 = c22 - qd;
        const float p2 = d00 * d00 + d11 * d11 + d22 * d22 + 2.0f * pp1;
        float l1, l2, l3;
        if (p2 < 1e-30f) {
            l1 = l2 = l3 = qd;
        } else {
            const float p = sqrtf(p2 * (1.0f / 6.0f));
            const float inv = 1.0f / p;
            const float e00 = d00 * inv, e11 = d11 * inv, e22 = d22 * inv;
            const float e01 = c01 * inv, e02 = c02 * inv, e12 = c12 * inv;
            float detB = e00 * (e11 * e22 - e12 * e12)
                       - e01 * (e01 * e22 - e12 * e02)
                       + e02 * (e01 * e12 - e11 * e02);
            float r = 0.5f * detB;
            r = fminf(1.0f, fmaxf(-1.0f, r));
            const float phi = acosf(r) * (1.0f / 3.0f);
            l1 = qd + 2.0f * p * __cosf(phi);                          // largest
            l3 = qd + 2.0f * p * __cosf(phi + 2.0943951023931953f);    // smallest
            l2 = 3.0f * qd - l1 - l3;
        }
        fr[73] = (l1 - l2) / l1;
        fr[74] = (l2 - l3) / l1;
        fr[75] = l3 / l1;
    }

    __syncthreads();   // weights + features visible

    const float* fr = fs[pl];
    const int f0 = subf * 38;

    float h[32];
#pragma unroll
    for (int j = 0; j < 32; ++j) h[j] = (subf == 0) ? b1s[subh * 32 + j] : 0.0f;

#pragma unroll 2
    for (int ff = 0; ff < 38; ++ff) {
        const int f = f0 + ff;
        const float v = fr[f];
        const float4* w4 = reinterpret_cast<const float4*>(w1s + f * 68 + subh * 32);
#pragma unroll
        for (int j4 = 0; j4 < 8; ++j4) {
            const float4 w = w4[j4];
            h[4 * j4 + 0] = fmaf(v, w.x, h[4 * j4 + 0]);
            h[4 * j4 + 1] = fmaf(v, w.y, h[4 * j4 + 1]);
            h[4 * j4 + 2] = fmaf(v, w.z, h[4 * j4 + 2]);
            h[4 * j4 + 3] = fmaf(v, w.w, h[4 * j4 + 3]);
        }
    }

    // combine feature halves (lanes differing in bit 1)
#pragma unroll
    for (int j = 0; j < 32; ++j) h[j] += __shfl_xor(h[j], 2, 64);

    float o0 = 0.f, o1 = 0.f, o2 = 0.f;
#pragma unroll
    for (int j = 0; j < 32; ++j) {
        const float r = fmaxf(h[j], 0.0f);
        const int jj = subh * 32 + j;
        o0 = fmaf(r, w2s[jj * 3 + 0], o0);
        o1 = fmaf(r, w2s[jj * 3 + 1], o1);
        o2 = fmaf(r, w2s[jj * 3 + 2], o2);
    }
    // combine hidden halves (lanes differing in bit 0)
    o0 += __shfl_xor(o0, 1, 64);
    o1 += __shfl_xor(o1, 1, 64);
    o2 += __shfl_xor(o2, 1, 64);

    if ((t & 3) == 0) {
        float* op = out + (size_t)gid * 3;
        op[0] = fmaxf(o0 + b2s[0], 0.0f);
        op[1] = fmaxf(o1 + b2s[1], 0.0f);
        op[2] = fmaxf(o2 + b2s[2], 0.0f);
    }
}

extern "C" void kernel_launch(void* const* d_in, const int* in_sizes, int n_in,
                              void* d_out, int out_size, void* d_ws, size_t ws_size,
                              hipStream_t stream) {
    const float* cloud = (const float*)d_in[0];   // [4,8192,3]
    const float* W1    = (const float*)d_in[1];   // [76,64]
    const float* b1    = (const float*)d_in[2];   // [64]
    const float* W2    = (const float*)d_in[3];   // [64,3]
    const float* b2    = (const float*)d_in[4];   // [3]
    float* out = (float*)d_out;                   // [4,8192,3]

    float4* pts4 = (float4*)d_ws;                                          // 512 KB
    unsigned short* knn = (unsigned short*)((char*)d_ws + 4 * NPTS * 16);  // 640 KB

    prep_kernel<<<dim3(128), dim3(256), 0, stream>>>(cloud, pts4);
    knn_kernel<<<dim3(512), dim3(1024), 0, stream>>>(pts4, knn);
    feat_mlp_kernel<<<dim3(512), dim3(256), 0, stream>>>(pts4, W1, b1, W2, b2, knn, out);
}